// Round 1
// baseline (622.936 us; speedup 1.0000x reference)
//
#include <hip/hip_runtime.h>

// RelationAwareAttention on gfx950.
// Pipeline: cvt(bf16) + Wt transpose -> QKV GEMM (MFMA bf16) -> fused
// relation-aware attention (online, no score materialization) -> O GEMM -> LN.
// All intermediate compute bf16 MFMA / fp32 accumulate; threshold is 2% absmax.

using u16 = unsigned short;
using u32 = unsigned int;

typedef __attribute__((ext_vector_type(8))) short bf16x8; // 8 bf16 = 4 VGPRs
typedef __attribute__((ext_vector_type(4))) float f32x4;

#define H_  16
#define NH_ 8
#define HD_ 32
#define L_  2048
#define E_  512
#define B_  2
#define M_  4096           // B_*L_
static constexpr float SCALE_ = 0.1767766952966369f; // 1/sqrt(32)

__device__ inline u16 f2bf(float x) {
  union { float f; u32 u; } v; v.f = x;
  u32 r = v.u + 0x7FFFu + ((v.u >> 16) & 1u);   // RNE
  return (u16)(r >> 16);
}

// ---------------- prep: fp32 -> bf16 activations ----------------
__global__ __launch_bounds__(256) void k_cvt3(const float* __restrict__ a, const float* __restrict__ b,
                                              const float* __restrict__ c,
                                              u16* __restrict__ oa, u16* __restrict__ ob, u16* __restrict__ oc) {
  int w = blockIdx.y;
  const float* s = (w == 0) ? a : (w == 1) ? b : c;
  u16* d = (w == 0) ? oa : (w == 1) ? ob : oc;
  size_t i = ((size_t)blockIdx.x * 256 + threadIdx.x) * 4;
  float4 v = *(const float4*)(s + i);
  uint2 pk;
  pk.x = (u32)f2bf(v.x) | ((u32)f2bf(v.y) << 16);
  pk.y = (u32)f2bf(v.z) | ((u32)f2bf(v.w) << 16);
  *(uint2*)(d + i) = pk;
}

// ---------------- prep: weight transpose + bf16 ----------------
// W stored [in,out]; B-fragment wants k-contiguous => produce Wt[out][in].
__global__ __launch_bounds__(256) void k_wtrans(const float* __restrict__ Wq, const float* __restrict__ Wk,
                                                const float* __restrict__ Wv, const float* __restrict__ Wo,
                                                u16* __restrict__ Tq, u16* __restrict__ Tk,
                                                u16* __restrict__ Tv, u16* __restrict__ To) {
  int z = blockIdx.z;
  const float* W = (z == 0) ? Wq : (z == 1) ? Wk : (z == 2) ? Wv : Wo;
  u16* T = (z == 0) ? Tq : (z == 1) ? Tk : (z == 2) ? Tv : To;
  __shared__ u16 tile[64][65];
  int r0 = blockIdx.y * 64, c0 = blockIdx.x * 64;
  int tw = threadIdx.x >> 6, tl = threadIdx.x & 63;
#pragma unroll
  for (int i = 0; i < 16; ++i) {
    int r = i * 4 + tw;
    tile[r][tl] = f2bf(W[(size_t)(r0 + r) * E_ + c0 + tl]);
  }
  __syncthreads();
#pragma unroll
  for (int i = 0; i < 16; ++i) {
    int r = i * 4 + tw;
    T[(size_t)(c0 + r) * E_ + r0 + tl] = tile[tl][r];
  }
}

// ---------------- 128x128 bf16 MFMA GEMM, K=512 ----------------
// mode 0: write bf16 head layout [B,H,L,HD]; mode 1: write fp32 [M,512].
__device__ inline void gemm_body(const u16* __restrict__ A, const u16* __restrict__ Bt,
                                 const float* __restrict__ bias, void* __restrict__ out, int mode) {
  __shared__ __align__(16) u16 As[128 * 72];
  __shared__ __align__(16) u16 Bs[128 * 72];
  const int tid = threadIdx.x;
  const int lane = tid & 63, wid = tid >> 6;
  const int m0 = blockIdx.x * 128, n0 = blockIdx.y * 128;
  const int wm = (wid >> 1) * 64, wn = (wid & 1) * 64;
  const int mrow = lane & 15, quad = lane >> 4;
  f32x4 acc[4][4] = {};
  for (int k0 = 0; k0 < 512; k0 += 64) {
    __syncthreads();
#pragma unroll
    for (int i = 0; i < 4; ++i) {
      int task = i * 256 + tid;
      int r = task >> 3, c = task & 7;
      *(uint4*)(As + r * 72 + c * 8) = *(const uint4*)(A + (size_t)(m0 + r) * 512 + k0 + c * 8);
      *(uint4*)(Bs + r * 72 + c * 8) = *(const uint4*)(Bt + (size_t)(n0 + r) * 512 + k0 + c * 8);
    }
    __syncthreads();
#pragma unroll
    for (int kk = 0; kk < 64; kk += 32) {
      bf16x8 af[4], bfr[4];
#pragma unroll
      for (int f = 0; f < 4; ++f)
        af[f] = *(const bf16x8*)(As + (wm + f * 16 + mrow) * 72 + kk + quad * 8);
#pragma unroll
      for (int f = 0; f < 4; ++f)
        bfr[f] = *(const bf16x8*)(Bs + (wn + f * 16 + mrow) * 72 + kk + quad * 8);
#pragma unroll
      for (int fm = 0; fm < 4; ++fm)
#pragma unroll
        for (int fn = 0; fn < 4; ++fn)
          acc[fm][fn] = __builtin_amdgcn_mfma_f32_16x16x32_bf16(af[fm], bfr[fn], acc[fm][fn], 0, 0, 0);
    }
  }
#pragma unroll
  for (int fn = 0; fn < 4; ++fn) {
    int gn = n0 + wn + fn * 16 + mrow;
    float bv = bias[gn];
#pragma unroll
    for (int fm = 0; fm < 4; ++fm) {
#pragma unroll
      for (int r = 0; r < 4; ++r) {
        int gm = m0 + wm + fm * 16 + quad * 4 + r;
        float v = acc[fm][fn][r] + bv;
        if (mode == 0) {
          int bb = gm >> 11, q = gm & (L_ - 1);
          int hh = gn >> 5, d = gn & (HD_ - 1);
          ((u16*)out)[(((size_t)(bb * H_ + hh)) * L_ + q) * HD_ + d] = f2bf(v);
        } else {
          ((float*)out)[(size_t)gm * E_ + gn] = v;
        }
      }
    }
  }
}

__global__ __launch_bounds__(256) void k_gemm_qkv(const u16* Xq, const u16* Xk, const u16* Xv,
                                                  const u16* Tq, const u16* Tk, const u16* Tv,
                                                  const float* bq, const float* bk, const float* bv,
                                                  u16* Qb, u16* Kb, u16* Vb) {
  int z = blockIdx.z;
  const u16* A = (z == 0) ? Xq : (z == 1) ? Xk : Xv;
  const u16* T = (z == 0) ? Tq : (z == 1) ? Tk : Tv;
  const float* bi = (z == 0) ? bq : (z == 1) ? bk : bv;
  u16* o = (z == 0) ? Qb : (z == 1) ? Kb : Vb;
  gemm_body(A, T, bi, o, 0);
}

__global__ __launch_bounds__(256) void k_gemm_o(const u16* A, const u16* T, const float* bi, float* Y) {
  gemm_body(A, T, bi, Y, 1);
}

// ---------------- fused relation-aware attention ----------------
// grid (L/64, H, B); 256 threads = 4 waves; wave w owns q rows w*16..w*16+15.
// Both head types: P = exp(s)*(w or 1); out = (P@V) / (sum P [+1e-6]).
__global__ __launch_bounds__(256) void k_attn(const u16* __restrict__ Qb, const u16* __restrict__ Kb,
                                              const u16* __restrict__ Vb, const float* __restrict__ relw,
                                              u16* __restrict__ AO) {
  const int tid = threadIdx.x, lane = tid & 63, wid = tid >> 6;
  const int q0 = blockIdx.x * 64;
  const int h = blockIdx.y, b = blockIdx.z;
  const bool isrel = (h >= NH_);
  const size_t headOff = ((size_t)(b * H_ + h)) * L_ * HD_;
  const float* wbase = isrel ? relw + ((size_t)(b * (H_ - NH_) + (h - NH_))) * L_ * L_ : nullptr;

  __shared__ __align__(16) u16 Qs[64 * 40];     // padded: stride 40 -> conflict-free b128
  __shared__ __align__(16) u16 Ks[64 * 40];
  __shared__ __align__(16) u16 Vts[32 * 72];    // V tile transposed [d][k]
  __shared__ __align__(16) u16 Ps[4][16 * 72];  // per-wave P (C-layout -> A-layout via LDS)

  { // stage Q tile once
    int r = tid >> 2, c = tid & 3;
    *(uint4*)(Qs + r * 40 + c * 8) = *(const uint4*)(Qb + headOff + (size_t)(q0 + r) * HD_ + c * 8);
  }
  __syncthreads();
  const int mrow = lane & 15, quad = lane >> 4;
  bf16x8 qa = *(const bf16x8*)(Qs + (wid * 16 + mrow) * 40 + quad * 8); // A-frag: m=lane&15, k=quad*8+j
  f32x4 accd[2] = {};       // out [16q x 32d], two 16-col halves, C-layout
  float den[4] = {0.f, 0.f, 0.f, 0.f};

  for (int kt = 0; kt < L_; kt += 64) {
    __syncthreads();
    if (tid < 128) { // V transpose staging: pack (k,k+1) pairs along rows d
      int p = tid >> 2, c = tid & 3;
      const u16* vsrc = Vb + headOff + (size_t)(kt + 2 * p) * HD_ + c * 8;
      uint4 v0 = *(const uint4*)(vsrc);
      uint4 v1 = *(const uint4*)(vsrc + HD_);
      const u16* s0 = (const u16*)&v0;
      const u16* s1 = (const u16*)&v1;
#pragma unroll
      for (int i = 0; i < 8; ++i) {
        u32 pk = (u32)s0[i] | ((u32)s1[i] << 16);
        *(u32*)(Vts + (c * 8 + i) * 72 + 2 * p) = pk;
      }
    } else { // K staging
      int t2 = tid - 128;
#pragma unroll
      for (int i = 0; i < 2; ++i) {
        int task = t2 * 2 + i;
        int r = task >> 2, c = task & 3;
        *(uint4*)(Ks + r * 40 + c * 8) = *(const uint4*)(Kb + headOff + (size_t)(kt + r) * HD_ + c * 8);
      }
    }
    __syncthreads();

    u16* pw = Ps[wid];
#pragma unroll
    for (int f = 0; f < 4; ++f) {
      bf16x8 kb = *(const bf16x8*)(Ks + (f * 16 + mrow) * 40 + quad * 8); // B-frag: n=lane&15, k=quad*8+j
      f32x4 z = {0.f, 0.f, 0.f, 0.f};
      f32x4 s = __builtin_amdgcn_mfma_f32_16x16x32_bf16(qa, kb, z, 0, 0, 0);
      int kg = kt + f * 16 + mrow; // C col = lane&15
#pragma unroll
      for (int r = 0; r < 4; ++r) { // C row = quad*4+r
        float e = __expf(s[r] * SCALE_);
        if (isrel) {
          int qg = q0 + wid * 16 + quad * 4 + r;
          e *= wbase[(size_t)qg * L_ + kg];
        }
        den[r] += e;
        pw[(quad * 4 + r) * 72 + f * 16 + mrow] = f2bf(e);
      }
    }
    asm volatile("s_waitcnt lgkmcnt(0)" ::: "memory"); // P visible to whole wave (wave-private tile)
#pragma unroll
    for (int kk = 0; kk < 2; ++kk) {
      bf16x8 pa = *(const bf16x8*)(pw + mrow * 72 + kk * 32 + quad * 8); // A-frag of P
#pragma unroll
      for (int dh = 0; dh < 2; ++dh) {
        bf16x8 vbf = *(const bf16x8*)(Vts + (dh * 16 + mrow) * 72 + kk * 32 + quad * 8); // B-frag of V
        accd[dh] = __builtin_amdgcn_mfma_f32_16x16x32_bf16(pa, vbf, accd[dh], 0, 0, 0);
      }
    }
  }

  // reduce den across the 16 lanes of each quad (cols of the S tile)
#pragma unroll
  for (int off = 1; off < 16; off <<= 1)
#pragma unroll
    for (int r = 0; r < 4; ++r) den[r] += __shfl_xor(den[r], off, 64);

  const float eps = isrel ? 1e-6f : 0.f;
#pragma unroll
  for (int dh = 0; dh < 2; ++dh)
#pragma unroll
    for (int r = 0; r < 4; ++r) {
      int qg = q0 + wid * 16 + quad * 4 + r;
      float o = accd[dh][r] / (den[r] + eps);
      AO[((size_t)(b * L_ + qg)) * E_ + h * HD_ + dh * 16 + mrow] = f2bf(o);
    }
}

// ---------------- LayerNorm ----------------
__global__ __launch_bounds__(256) void k_ln(const float* __restrict__ Y, const float* __restrict__ gamma,
                                            const float* __restrict__ beta, float* __restrict__ out) {
  int row = blockIdx.x, tid = threadIdx.x;
  const float* y = Y + (size_t)row * E_;
  float2 v = *(const float2*)(y + tid * 2);
  float s = v.x + v.y, sq = v.x * v.x + v.y * v.y;
#pragma unroll
  for (int off = 1; off < 64; off <<= 1) {
    s += __shfl_xor(s, off, 64);
    sq += __shfl_xor(sq, off, 64);
  }
  __shared__ float ss[4], ssq[4];
  int wid = tid >> 6, lane = tid & 63;
  if (lane == 0) { ss[wid] = s; ssq[wid] = sq; }
  __syncthreads();
  s = ss[0] + ss[1] + ss[2] + ss[3];
  sq = ssq[0] + ssq[1] + ssq[2] + ssq[3];
  float mean = s * (1.f / E_);
  float var = sq * (1.f / E_) - mean * mean;
  float rstd = rsqrtf(var + 1e-5f);
  float2 g = *(const float2*)(gamma + tid * 2);
  float2 be = *(const float2*)(beta + tid * 2);
  float2 o;
  o.x = (v.x - mean) * rstd * g.x + be.x;
  o.y = (v.y - mean) * rstd * g.y + be.y;
  *(float2*)(out + (size_t)row * E_ + tid * 2) = o;
}

extern "C" void kernel_launch(void* const* d_in, const int* in_sizes, int n_in,
                              void* d_out, int out_size, void* d_ws, size_t ws_size,
                              hipStream_t stream) {
  const float* query = (const float*)d_in[0];
  const float* key   = (const float*)d_in[1];
  const float* value = (const float*)d_in[2];
  const float* relw  = (const float*)d_in[3];
  const float* Wq = (const float*)d_in[4];
  const float* bq = (const float*)d_in[5];
  const float* Wk = (const float*)d_in[6];
  const float* bk = (const float*)d_in[7];
  const float* Wv = (const float*)d_in[8];
  const float* bv = (const float*)d_in[9];
  const float* Wo = (const float*)d_in[10];
  const float* bo = (const float*)d_in[11];
  const float* gamma = (const float*)d_in[12];
  const float* beta  = (const float*)d_in[13];

  char* ws = (char*)d_ws;
  u16* Xq = (u16*)(ws + 0);          // 4 MB each
  u16* Xk = (u16*)(ws + 4194304);
  u16* Xv = (u16*)(ws + 8388608);
  u16* Tq = (u16*)(ws + 12582912);   // 512 KB each
  u16* Tk = (u16*)(ws + 13107200);
  u16* Tv = (u16*)(ws + 13631488);
  u16* To = (u16*)(ws + 14155776);
  u16* Qb = (u16*)(ws + 14680064);   // 4 MB each, [B,H,L,HD] bf16
  u16* Kb = (u16*)(ws + 18874368);
  u16* Vb = (u16*)(ws + 23068672);
  u16* AO = (u16*)(ws + 27262976);   // 4 MB, [M,E] bf16
  float* Y = (float*)(ws + 0);       // 8 MB fp32, reuses Xq/Xk (dead after QKV GEMMs)

  k_cvt3<<<dim3(2048, 3, 1), 256, 0, stream>>>(query, key, value, Xq, Xk, Xv);
  k_wtrans<<<dim3(8, 8, 4), 256, 0, stream>>>(Wq, Wk, Wv, Wo, Tq, Tk, Tv, To);
  k_gemm_qkv<<<dim3(32, 4, 3), 256, 0, stream>>>(Xq, Xk, Xv, Tq, Tk, Tv, bq, bk, bv, Qb, Kb, Vb);
  k_attn<<<dim3(32, 16, 2), 256, 0, stream>>>(Qb, Kb, Vb, relw, AO);
  k_gemm_o<<<dim3(32, 4, 1), 256, 0, stream>>>(AO, To, bo, Y);
  k_ln<<<4096, 256, 0, stream>>>(Y, gamma, beta, (float*)d_out);
}

// Round 2
// 494.010 us; speedup vs baseline: 1.2610x; 1.2610x over previous
//
#include <hip/hip_runtime.h>

// RelationAwareAttention on gfx950.
// cvt(bf16) + Wt transpose -> QKV GEMM (MFMA bf16, LDS-transposed epilogue) ->
// fused relation-aware attention (k-split x2, relw staged via LDS, fp16/fp32
// partials) -> combine -> O GEMM -> LN.

using u16 = unsigned short;
using u32 = unsigned int;

typedef __attribute__((ext_vector_type(8))) short bf16x8; // 8 bf16 = 4 VGPRs
typedef __attribute__((ext_vector_type(4))) float f32x4;

#define H_  16
#define NH_ 8
#define HD_ 32
#define L_  2048
#define E_  512
#define B_  2
#define M_  4096           // B_*L_
#define KSPLIT 2
static constexpr float SCALE_ = 0.1767766952966369f; // 1/sqrt(32)

__device__ inline u16 f2bf(float x) {
  union { float f; u32 u; } v; v.f = x;
  u32 r = v.u + 0x7FFFu + ((v.u >> 16) & 1u);   // RNE
  return (u16)(r >> 16);
}
__device__ inline float bf2f(u16 x) {
  union { u32 u; float f; } v; v.u = ((u32)x) << 16; return v.f;
}
__device__ inline u16 f2h(float x) {
  union { _Float16 h; u16 u; } v; v.h = (_Float16)x; return v.u;
}
__device__ inline float h2f(u16 x) {
  union { u16 u; _Float16 h; } v; v.u = x; return (float)v.h;
}

// ---------------- prep: fp32 -> bf16 activations ----------------
__global__ __launch_bounds__(256) void k_cvt3(const float* __restrict__ a, const float* __restrict__ b,
                                              const float* __restrict__ c,
                                              u16* __restrict__ oa, u16* __restrict__ ob, u16* __restrict__ oc) {
  int w = blockIdx.y;
  const float* s = (w == 0) ? a : (w == 1) ? b : c;
  u16* d = (w == 0) ? oa : (w == 1) ? ob : oc;
  size_t i = ((size_t)blockIdx.x * 256 + threadIdx.x) * 4;
  float4 v = *(const float4*)(s + i);
  uint2 pk;
  pk.x = (u32)f2bf(v.x) | ((u32)f2bf(v.y) << 16);
  pk.y = (u32)f2bf(v.z) | ((u32)f2bf(v.w) << 16);
  *(uint2*)(d + i) = pk;
}

// ---------------- prep: weight transpose + bf16 ----------------
__global__ __launch_bounds__(256) void k_wtrans(const float* __restrict__ Wq, const float* __restrict__ Wk,
                                                const float* __restrict__ Wv, const float* __restrict__ Wo,
                                                u16* __restrict__ Tq, u16* __restrict__ Tk,
                                                u16* __restrict__ Tv, u16* __restrict__ To) {
  int z = blockIdx.z;
  const float* W = (z == 0) ? Wq : (z == 1) ? Wk : (z == 2) ? Wv : Wo;
  u16* T = (z == 0) ? Tq : (z == 1) ? Tk : (z == 2) ? Tv : To;
  __shared__ u16 tile[64][65];
  int r0 = blockIdx.y * 64, c0 = blockIdx.x * 64;
  int tw = threadIdx.x >> 6, tl = threadIdx.x & 63;
#pragma unroll
  for (int i = 0; i < 16; ++i) {
    int r = i * 4 + tw;
    tile[r][tl] = f2bf(W[(size_t)(r0 + r) * E_ + c0 + tl]);
  }
  __syncthreads();
#pragma unroll
  for (int i = 0; i < 16; ++i) {
    int r = i * 4 + tw;
    T[(size_t)(c0 + r) * E_ + r0 + tl] = tile[tl][r];
  }
}

// ---------------- 128x128 bf16 MFMA GEMM, K=512 ----------------
// MODE 0: write bf16 head layout [B,H,L,HD] via LDS-transposed vector stores.
// MODE 1: write fp32 [M,512].
template <int MODE>
__device__ inline void gemm_body(const u16* __restrict__ A, const u16* __restrict__ Bt,
                                 const float* __restrict__ bias, void* __restrict__ out) {
  __shared__ __align__(16) u16 smem[2 * 128 * 72];
  u16* As = smem;
  u16* Bs = smem + 128 * 72;
  const int tid = threadIdx.x;
  const int lane = tid & 63, wid = tid >> 6;
  const int m0 = blockIdx.x * 128, n0 = blockIdx.y * 128;
  const int wm = (wid >> 1) * 64, wn = (wid & 1) * 64;
  const int mrow = lane & 15, quad = lane >> 4;
  f32x4 acc[4][4] = {};
  for (int k0 = 0; k0 < 512; k0 += 64) {
    __syncthreads();
#pragma unroll
    for (int i = 0; i < 4; ++i) {
      int task = i * 256 + tid;
      int r = task >> 3, c = task & 7;
      *(uint4*)(As + r * 72 + c * 8) = *(const uint4*)(A + (size_t)(m0 + r) * 512 + k0 + c * 8);
      *(uint4*)(Bs + r * 72 + c * 8) = *(const uint4*)(Bt + (size_t)(n0 + r) * 512 + k0 + c * 8);
    }
    __syncthreads();
#pragma unroll
    for (int kk = 0; kk < 64; kk += 32) {
      bf16x8 af[4], bfr[4];
#pragma unroll
      for (int f = 0; f < 4; ++f)
        af[f] = *(const bf16x8*)(As + (wm + f * 16 + mrow) * 72 + kk + quad * 8);
#pragma unroll
      for (int f = 0; f < 4; ++f)
        bfr[f] = *(const bf16x8*)(Bs + (wn + f * 16 + mrow) * 72 + kk + quad * 8);
#pragma unroll
      for (int fm = 0; fm < 4; ++fm)
#pragma unroll
        for (int fn = 0; fn < 4; ++fn)
          acc[fm][fn] = __builtin_amdgcn_mfma_f32_16x16x32_bf16(af[fm], bfr[fn], acc[fm][fn], 0, 0, 0);
    }
  }
  if (MODE == 0) {
    // epilogue: wave-local LDS transpose -> 16B vector stores to [B,H,L,HD] bf16
    __syncthreads();
    u16* wscr = smem + wid * (64 * 72);   // 4*64*72 = 18432 u16, exact fit
#pragma unroll
    for (int fn = 0; fn < 4; ++fn) {
      float bv = bias[n0 + wn + fn * 16 + mrow];
#pragma unroll
      for (int fm = 0; fm < 4; ++fm)
#pragma unroll
        for (int r = 0; r < 4; ++r)
          wscr[(fm * 16 + quad * 4 + r) * 72 + fn * 16 + mrow] = f2bf(acc[fm][fn][r] + bv);
    }
    asm volatile("s_waitcnt lgkmcnt(0)" ::: "memory"); // wave-private scratch
    const int hg0 = (n0 + wn) >> 5;
#pragma unroll
    for (int c = 0; c < 8; ++c) {
      int linear = c * 64 + lane;
      int hh = linear >> 8;          // which of the wave's two heads
      int rem = linear & 255;
      int lm = rem >> 2, j = rem & 3;
      uint4 vv = *(const uint4*)(wscr + lm * 72 + hh * 32 + j * 8);
      int gm = m0 + wm + lm;
      int bb = gm >> 11, q = gm & (L_ - 1);
      *(uint4*)((u16*)out + (((size_t)(bb * H_ + hg0 + hh)) * L_ + q) * HD_ + j * 8) = vv;
    }
  } else {
#pragma unroll
    for (int fn = 0; fn < 4; ++fn) {
      int gn = n0 + wn + fn * 16 + mrow;
      float bv = bias[gn];
#pragma unroll
      for (int fm = 0; fm < 4; ++fm)
#pragma unroll
        for (int r = 0; r < 4; ++r) {
          int gm = m0 + wm + fm * 16 + quad * 4 + r;
          ((float*)out)[(size_t)gm * E_ + gn] = acc[fm][fn][r] + bv;
        }
    }
  }
}

__global__ __launch_bounds__(256) void k_gemm_qkv(const u16* Xq, const u16* Xk, const u16* Xv,
                                                  const u16* Tq, const u16* Tk, const u16* Tv,
                                                  const float* bq, const float* bk, const float* bv,
                                                  u16* Qb, u16* Kb, u16* Vb) {
  int z = blockIdx.z;
  const u16* A = (z == 0) ? Xq : (z == 1) ? Xk : Xv;
  const u16* T = (z == 0) ? Tq : (z == 1) ? Tk : Tv;
  const float* bi = (z == 0) ? bq : (z == 1) ? bk : bv;
  u16* o = (z == 0) ? Qb : (z == 1) ? Kb : Vb;
  gemm_body<0>(A, T, bi, o);
}

__global__ __launch_bounds__(256) void k_gemm_o(const u16* A, const u16* T, const float* bi, float* Y) {
  gemm_body<1>(A, T, bi, Y);
}

// ---------------- fused relation-aware attention (k-split) ----------------
// grid (L/64, H, B*KSPLIT); 256 threads = 4 waves; wave w owns q rows w*16..+15.
// Each block covers keys [s*1024, s*1024+1024) and writes fp16 partial
// numerators Pnum[s][b][h][q][d] and fp32 partial denominators Pden[s][b][h][q].
__global__ __launch_bounds__(256) void k_attn(const u16* __restrict__ Qb, const u16* __restrict__ Kb,
                                              const u16* __restrict__ Vb, const float* __restrict__ relw,
                                              u16* __restrict__ Pnum, float* __restrict__ Pden) {
  const int tid = threadIdx.x, lane = tid & 63, wid = tid >> 6;
  const int q0 = blockIdx.x * 64;
  const int h = blockIdx.y;
  const int b = blockIdx.z & (B_ - 1), s = blockIdx.z >> 1;
  const int kbase = s * (L_ / KSPLIT);
  const bool isrel = (h >= NH_);
  const size_t headOff = ((size_t)(b * H_ + h)) * L_ * HD_;
  const float* wbase = isrel ? relw + ((size_t)(b * (H_ - NH_) + (h - NH_))) * L_ * L_ : nullptr;

  __shared__ __align__(16) u16 Qs[64 * 40];
  __shared__ __align__(16) u16 Ks[64 * 40];
  __shared__ __align__(16) u16 Vts[32 * 72];    // V tile transposed [d][k]
  __shared__ __align__(16) u16 Ps[4][16 * 72];  // per-wave P (C->A layout via LDS)
  __shared__ __align__(16) u16 Ws[64 * 68];     // relw tile bf16 [q][k]

  { // stage Q tile once
    int r = tid >> 2, c = tid & 3;
    *(uint4*)(Qs + r * 40 + c * 8) = *(const uint4*)(Qb + headOff + (size_t)(q0 + r) * HD_ + c * 8);
  }
  __syncthreads();
  const int mrow = lane & 15, quad = lane >> 4;
  bf16x8 qa = *(const bf16x8*)(Qs + (wid * 16 + mrow) * 40 + quad * 8);
  f32x4 accd[2] = {};
  float den[4] = {0.f, 0.f, 0.f, 0.f};

  for (int kt = kbase; kt < kbase + L_ / KSPLIT; kt += 64) {
    __syncthreads();
    if (tid < 128) { // V transpose staging
      int p = tid >> 2, c = tid & 3;
      const u16* vsrc = Vb + headOff + (size_t)(kt + 2 * p) * HD_ + c * 8;
      uint4 v0 = *(const uint4*)(vsrc);
      uint4 v1 = *(const uint4*)(vsrc + HD_);
      const u16* s0 = (const u16*)&v0;
      const u16* s1 = (const u16*)&v1;
#pragma unroll
      for (int i = 0; i < 8; ++i) {
        u32 pk = (u32)s0[i] | ((u32)s1[i] << 16);
        *(u32*)(Vts + (c * 8 + i) * 72 + 2 * p) = pk;
      }
    } else { // K staging
      int t2 = tid - 128;
#pragma unroll
      for (int i = 0; i < 2; ++i) {
        int task = t2 * 2 + i;
        int r = task >> 2, c = task & 3;
        *(uint4*)(Ks + r * 40 + c * 8) = *(const uint4*)(Kb + headOff + (size_t)(kt + r) * HD_ + c * 8);
      }
    }
    if (isrel) { // relw tile: coalesced float4 -> bf16 LDS (stride 68 = conflict-free readback)
      int q = tid >> 2, kc = (tid & 3) * 4;
      const float* wsrc = wbase + (size_t)(q0 + q) * L_ + kt + kc;
#pragma unroll
      for (int j = 0; j < 4; ++j) {
        float4 w4 = *(const float4*)(wsrc + j * 16);
        uint2 pk;
        pk.x = (u32)f2bf(w4.x) | ((u32)f2bf(w4.y) << 16);
        pk.y = (u32)f2bf(w4.z) | ((u32)f2bf(w4.w) << 16);
        *(uint2*)(Ws + q * 68 + kc + j * 16) = pk;
      }
    }
    __syncthreads();

    u16* pw = Ps[wid];
#pragma unroll
    for (int f = 0; f < 4; ++f) {
      bf16x8 kb = *(const bf16x8*)(Ks + (f * 16 + mrow) * 40 + quad * 8);
      f32x4 z = {0.f, 0.f, 0.f, 0.f};
      f32x4 sc = __builtin_amdgcn_mfma_f32_16x16x32_bf16(qa, kb, z, 0, 0, 0);
#pragma unroll
      for (int r = 0; r < 4; ++r) { // C: row=quad*4+r (q), col=mrow (k)
        float e = __expf(sc[r] * SCALE_);
        if (isrel)
          e *= bf2f(Ws[(wid * 16 + quad * 4 + r) * 68 + f * 16 + mrow]);
        den[r] += e;
        pw[(quad * 4 + r) * 72 + f * 16 + mrow] = f2bf(e);
      }
    }
    asm volatile("s_waitcnt lgkmcnt(0)" ::: "memory"); // P visible (wave-private tile)
#pragma unroll
    for (int kk = 0; kk < 2; ++kk) {
      bf16x8 pa = *(const bf16x8*)(pw + mrow * 72 + kk * 32 + quad * 8);
#pragma unroll
      for (int dh = 0; dh < 2; ++dh) {
        bf16x8 vbf = *(const bf16x8*)(Vts + (dh * 16 + mrow) * 72 + kk * 32 + quad * 8);
        accd[dh] = __builtin_amdgcn_mfma_f32_16x16x32_bf16(pa, vbf, accd[dh], 0, 0, 0);
      }
    }
  }

  // reduce den across the 16 lanes of each quad
#pragma unroll
  for (int off = 1; off < 16; off <<= 1)
#pragma unroll
    for (int r = 0; r < 4; ++r) den[r] += __shfl_xor(den[r], off, 64);

  const size_t pidx = ((size_t)(s * B_ + b) * H_ + h) * L_;
#pragma unroll
  for (int dh = 0; dh < 2; ++dh)
#pragma unroll
    for (int r = 0; r < 4; ++r) {
      int qg = q0 + wid * 16 + quad * 4 + r;
      Pnum[(pidx + qg) * HD_ + dh * 16 + mrow] = f2h(accd[dh][r]);
    }
  if (mrow == 0) {
    int qg = q0 + wid * 16 + quad * 4;
    float4 dv = {den[0], den[1], den[2], den[3]};
    *(float4*)(Pden + pidx + qg) = dv;
  }
}

// ---------------- combine partials -> AO bf16 [M,E] ----------------
__global__ __launch_bounds__(256) void k_combine(const u16* __restrict__ Pnum, const float* __restrict__ Pden,
                                                 u16* __restrict__ AO) {
  int row = blockIdx.x;               // b*L + q
  int tid = threadIdx.x;
  int b = row >> 11, q = row & (L_ - 1);
  int e0 = tid * 2;
  int h = e0 >> 5, d = e0 & (HD_ - 1);
  size_t i0 = ((size_t)(0 * B_ + b) * H_ + h) * L_ + q;
  size_t i1 = ((size_t)(1 * B_ + b) * H_ + h) * L_ + q;
  u32 n0 = *(const u32*)(Pnum + i0 * HD_ + d);
  u32 n1 = *(const u32*)(Pnum + i1 * HD_ + d);
  float den = Pden[i0] + Pden[i1] + ((h >= NH_) ? 1e-6f : 0.f);
  float rinv = 1.0f / den;
  float x = (h2f((u16)n0) + h2f((u16)n1)) * rinv;
  float y = (h2f((u16)(n0 >> 16)) + h2f((u16)(n1 >> 16))) * rinv;
  u32 pk = (u32)f2bf(x) | ((u32)f2bf(y) << 16);
  *(u32*)(AO + (size_t)row * E_ + e0) = pk;
}

// ---------------- LayerNorm ----------------
__global__ __launch_bounds__(256) void k_ln(const float* __restrict__ Y, const float* __restrict__ gamma,
                                            const float* __restrict__ beta, float* __restrict__ out) {
  int row = blockIdx.x, tid = threadIdx.x;
  const float* y = Y + (size_t)row * E_;
  float2 v = *(const float2*)(y + tid * 2);
  float s = v.x + v.y, sq = v.x * v.x + v.y * v.y;
#pragma unroll
  for (int off = 1; off < 64; off <<= 1) {
    s += __shfl_xor(s, off, 64);
    sq += __shfl_xor(sq, off, 64);
  }
  __shared__ float ss[4], ssq[4];
  int wid = tid >> 6, lane = tid & 63;
  if (lane == 0) { ss[wid] = s; ssq[wid] = sq; }
  __syncthreads();
  s = ss[0] + ss[1] + ss[2] + ss[3];
  sq = ssq[0] + ssq[1] + ssq[2] + ssq[3];
  float mean = s * (1.f / E_);
  float var = sq * (1.f / E_) - mean * mean;
  float rstd = rsqrtf(var + 1e-5f);
  float2 g = *(const float2*)(gamma + tid * 2);
  float2 be = *(const float2*)(beta + tid * 2);
  float2 o;
  o.x = (v.x - mean) * rstd * g.x + be.x;
  o.y = (v.y - mean) * rstd * g.y + be.y;
  *(float2*)(out + (size_t)row * E_ + tid * 2) = o;
}

extern "C" void kernel_launch(void* const* d_in, const int* in_sizes, int n_in,
                              void* d_out, int out_size, void* d_ws, size_t ws_size,
                              hipStream_t stream) {
  const float* query = (const float*)d_in[0];
  const float* key   = (const float*)d_in[1];
  const float* value = (const float*)d_in[2];
  const float* relw  = (const float*)d_in[3];
  const float* Wq = (const float*)d_in[4];
  const float* bq = (const float*)d_in[5];
  const float* Wk = (const float*)d_in[6];
  const float* bk = (const float*)d_in[7];
  const float* Wv = (const float*)d_in[8];
  const float* bv = (const float*)d_in[9];
  const float* Wo = (const float*)d_in[10];
  const float* bo = (const float*)d_in[11];
  const float* gamma = (const float*)d_in[12];
  const float* beta  = (const float*)d_in[13];

  char* ws = (char*)d_ws;
  u16* Xq = (u16*)(ws + 0);          // 4 MB each (dead after QKV GEMM)
  u16* Xk = (u16*)(ws + 4194304);
  u16* Xv = (u16*)(ws + 8388608);
  u16* Tq = (u16*)(ws + 12582912);   // 512 KB each
  u16* Tk = (u16*)(ws + 13107200);
  u16* Tv = (u16*)(ws + 13631488);
  u16* To = (u16*)(ws + 14155776);
  u16* Qb = (u16*)(ws + 14680064);   // 4 MB each, [B,H,L,HD] bf16
  u16* Kb = (u16*)(ws + 18874368);
  u16* Vb = (u16*)(ws + 23068672);
  u16* AO = (u16*)(ws + 27262976);   // 4 MB, [M,E] bf16
  // partials overlay the dead X region (lifetime: attn..combine)
  u16*   Pnum = (u16*)(ws + 0);      // 2*2*16*2048*32 fp16 = 8.39 MB
  float* Pden = (float*)(ws + 8388608); // 512 KB (inside dead Xv)
  float* Y = (float*)(ws + 0);       // 8 MB fp32 (after combine; Pnum dead)

  k_cvt3<<<dim3(2048, 3, 1), 256, 0, stream>>>(query, key, value, Xq, Xk, Xv);
  k_wtrans<<<dim3(8, 8, 4), 256, 0, stream>>>(Wq, Wk, Wv, Wo, Tq, Tk, Tv, To);
  k_gemm_qkv<<<dim3(32, 4, 3), 256, 0, stream>>>(Xq, Xk, Xv, Tq, Tk, Tv, bq, bk, bv, Qb, Kb, Vb);
  k_attn<<<dim3(32, 16, B_ * KSPLIT), 256, 0, stream>>>(Qb, Kb, Vb, relw, Pnum, Pden);
  k_combine<<<M_, 256, 0, stream>>>(Pnum, Pden, AO);
  k_gemm_o<<<dim3(32, 4, 1), 256, 0, stream>>>(AO, To, bo, Y);
  k_ln<<<M_, 256, 0, stream>>>(Y, gamma, beta, (float*)d_out);
}